// Round 4
// baseline (183.288 us; speedup 1.0000x reference)
//
#include <hip/hip_runtime.h>
#include <hip/hip_bf16.h>

#define NB     8
#define NPTS   4096
#define KSEL   16
#define WAVES  8            // waves per block = candidate slices
#define CHUNK  (NPTS/WAVES) // 512 candidates per wave
#define NSLOTS 64
#define HALF   (NB * NPTS)  // 32768 points per array

// Unconditional sorted-ascending top-16 insert via med3 (15 independent med3 + 1 min).
__device__ __forceinline__ void insert16(float (&h)[KSEL], float d) {
#pragma unroll
  for (int j = KSEL - 1; j > 0; --j)
    h[j] = __builtin_amdgcn_fmed3f(d, h[j - 1], h[j]);
  h[0] = fminf(h[0], d);
}

__device__ __forceinline__ void ce(float& a, float& b) {
  const float lo = fminf(a, b), hi = fmaxf(a, b);
  a = lo; b = hi;
}

// Lane-local merge of two sorted-asc 16-lists -> sorted smallest-16 of the union.
__device__ __forceinline__ void merge16_arr(float (&h)[KSEL], const float (&g)[KSEL]) {
  float c[KSEL];
#pragma unroll
  for (int i = 0; i < KSEL; ++i) c[i] = fminf(h[i], g[KSEL - 1 - i]);
#pragma unroll
  for (int d = 8; d >= 1; d >>= 1) {
#pragma unroll
    for (int i = 0; i < KSEL; ++i)
      if ((i & d) == 0) ce(c[i], c[i + d]);
  }
#pragma unroll
  for (int i = 0; i < KSEL; ++i) h[i] = c[i];
}

// Pack candidates as (-2x, -2y, -2z, |c|^2): distance sans query-norm = 4 VALU ops.
extern "C" __global__ __launch_bounds__(256)
void prep_kernel(const float* __restrict__ gts, const float* __restrict__ preds,
                 float4* __restrict__ pk) {
  const int i = blockIdx.x * 256 + threadIdx.x;   // 0..2*HALF-1
  const float* __restrict__ src = (i < HALF) ? preds : gts;
  const int j = (i < HALF) ? i : i - HALF;
  const float x = src[3 * j], y = src[3 * j + 1], z = src[3 * j + 2];
  pk[i] = make_float4(-2.f * x, -2.f * y, -2.f * z, fmaf(x, x, fmaf(y, y, z * z)));
}

extern "C" __global__ void init_acc(double* acc) {
  const int t = threadIdx.x;
  if (t < 3 * NSLOTS) acc[t] = 0.0;
}

// lane = query point (64 per block), wave = candidate-eighth. Candidate stream is
// wave-uniform -> scalar loads (SGPR broadcast), zero LDS / zero addressing VALU
// in the hot loop. Cross-wave merge via 3-stage LDS tree of sorted-16 lists.
extern "C" __global__ __launch_bounds__(512, 4)
void fused_kernel(const float* __restrict__ gts, const float* __restrict__ preds,
                  const float4* __restrict__ pk, double* __restrict__ acc) {
  __shared__ float m1[4][64][KSEL];
  __shared__ float m2[4][64][KSEL];
  __shared__ float m3[4][64];

  const int t    = threadIdx.x;
  const int lane = t & 63;
  const int w    = __builtin_amdgcn_readfirstlane(t >> 6);  // wave id, provably uniform
  const int b    = blockIdx.y;
  const int pt   = blockIdx.x * 64 + lane;

  const float* __restrict__ gq = gts + ((size_t)b * NPTS + pt) * 3;
  const float qx = gq[0], qy = gq[1], qz = gq[2];
  const float qn = fmaf(qx, qx, fmaf(qy, qy, qz * qz));
  const float* __restrict__ pq = preds + ((size_t)b * NPTS + pt) * 3;
  const float px = pq[0], py = pq[1], pz = pq[2];
  const float pn = fmaf(px, px, fmaf(py, py, pz * pz));

  float h1[KSEL], h2[KSEL];
#pragma unroll
  for (int i = 0; i < KSEL; ++i) { h1[i] = 1e30f; h2[i] = 1e30f; }
  float bw = 1e30f;

  // Wave-uniform candidate stream bases.
  const float4* __restrict__ cp = pk + (size_t)b * NPTS + w * CHUNK;          // preds
  const float4* __restrict__ cg = pk + HALF + (size_t)b * NPTS + w * CHUNK;   // gts

#pragma unroll 4
  for (int j = 0; j < CHUNK; ++j) {
    const float4 c4 = cp[j];                    // scalar (SGPR) broadcast
    float s = qx * c4.x;
    s = fmaf(qy, c4.y, s);
    s = fmaf(qz, c4.z, s);
    insert16(h1, s + c4.w);
  }

#pragma unroll 4
  for (int j = 0; j < CHUNK; ++j) {
    const float4 c4 = cg[j];
    float s = qx * c4.x;
    s = fmaf(qy, c4.y, s);
    s = fmaf(qz, c4.z, s);
    insert16(h2, s + c4.w);
    float s2 = px * c4.x;
    s2 = fmaf(py, c4.y, s2);
    s2 = fmaf(pz, c4.z, s2);
    bw = fminf(bw, s2 + c4.w);                  // loss_1 partial (query = pred point)
  }

  // ---- cross-wave merge: 8 -> 4 -> 2 -> 1 ----
  float g[KSEL];
#define WRITE_SLOT(S)                                                       \
  do {                                                                      \
    _Pragma("unroll") for (int i = 0; i < KSEL; ++i) {                      \
      m1[S][lane][i] = h1[i]; m2[S][lane][i] = h2[i];                       \
    }                                                                       \
    m3[S][lane] = bw;                                                       \
  } while (0)
#define MERGE_SLOT(S)                                                       \
  do {                                                                      \
    _Pragma("unroll") for (int i = 0; i < KSEL; ++i) g[i] = m1[S][lane][i]; \
    merge16_arr(h1, g);                                                     \
    _Pragma("unroll") for (int i = 0; i < KSEL; ++i) g[i] = m2[S][lane][i]; \
    merge16_arr(h2, g);                                                     \
    bw = fminf(bw, m3[S][lane]);                                            \
  } while (0)

  __syncthreads();
  if (w >= 4) WRITE_SLOT(w - 4);
  __syncthreads();
  if (w < 4) MERGE_SLOT(w);
  __syncthreads();
  if (w == 2 || w == 3) WRITE_SLOT(w - 2);
  __syncthreads();
  if (w < 2) MERGE_SLOT(w);
  __syncthreads();
  if (w == 1) WRITE_SLOT(0);
  __syncthreads();

  if (w == 0) {
    MERGE_SLOT(0);
    float v1 = bw + pn;        // loss_1 term for pred point pt
    float v2 = h1[0] + qn;     // loss_2 term for gt point pt
    float v3 = 0.0f;           // density term (query norms cancel)
#pragma unroll
    for (int i = 0; i < KSEL; ++i) {
      const float df = h1[i] - h2[i];
      v3 = fmaf(df, df, v3);
    }
#pragma unroll
    for (int off = 32; off >= 1; off >>= 1) {
      v1 += __shfl_xor(v1, off);
      v2 += __shfl_xor(v2, off);
      v3 += __shfl_xor(v3, off);
    }
    if (lane == 0) {
      const int slot = (blockIdx.x + blockIdx.y * 17) & (NSLOTS - 1);
      atomicAdd(&acc[0 * NSLOTS + slot], (double)v1);
      atomicAdd(&acc[1 * NSLOTS + slot], (double)v2);
      atomicAdd(&acc[2 * NSLOTS + slot], (double)v3);
    }
  }
#undef WRITE_SLOT
#undef MERGE_SLOT
}

extern "C" __global__ void finalize_kernel(const double* __restrict__ acc,
                                           float* __restrict__ out) {
  const int l = threadIdx.x;  // 64 threads
  double a = acc[l], b = acc[NSLOTS + l], c = acc[2 * NSLOTS + l];
#pragma unroll
  for (int off = 32; off >= 1; off >>= 1) {
    a += __shfl_xor(a, off);
    b += __shfl_xor(b, off);
    c += __shfl_xor(c, off);
  }
  if (l == 0) {
    const double loss1 = a / (double)((size_t)NB * NPTS);
    const double loss2 = b / (double)((size_t)NB * NPTS);
    const double dens  = c / (double)((size_t)NB * NPTS * KSEL);
    out[0] = (float)(loss1 + loss2);
    out[1] = (float)dens;
  }
}

extern "C" void kernel_launch(void* const* d_in, const int* in_sizes, int n_in,
                              void* d_out, int out_size, void* d_ws, size_t ws_size,
                              hipStream_t stream) {
  const float* gts   = (const float*)d_in[0];
  const float* preds = (const float*)d_in[1];
  float4* pk  = (float4*)d_ws;                          // 2*HALF float4 = 1 MiB
  double* acc = (double*)((char*)d_ws + 2 * HALF * sizeof(float4));
  float*  out = (float*)d_out;

  hipLaunchKernelGGL(prep_kernel, dim3(2 * HALF / 256), dim3(256), 0, stream,
                     gts, preds, pk);
  hipLaunchKernelGGL(init_acc, dim3(1), dim3(256), 0, stream, acc);
  hipLaunchKernelGGL(fused_kernel, dim3(NPTS / 64, NB), dim3(512), 0, stream,
                     gts, preds, pk, acc);
  hipLaunchKernelGGL(finalize_kernel, dim3(1), dim3(64), 0, stream, acc, out);
}

// Round 5
// 143.346 us; speedup vs baseline: 1.2786x; 1.2786x over previous
//
#include <hip/hip_runtime.h>
#include <hip/hip_bf16.h>

#define NB      8
#define NPTS    4096
#define KSEL    16
#define HSZ     4          // per-lane list size (32-way split -> top-4 safe)
#define QPB     16         // queries per block
#define THREADS 512
#define NSLOTS  64

// ---- small sorted-list machinery --------------------------------------------
__device__ __forceinline__ void ce(float& a, float& b) {
  const float lo = fminf(a, b), hi = fmaxf(a, b);
  a = lo; b = hi;
}

// sorted-asc insert, keep smallest HSZ: h'[j] = med3(d, h[j-1], h[j])
__device__ __forceinline__ void insert4(float (&h)[HSZ], float d) {
  h[3] = __builtin_amdgcn_fmed3f(d, h[2], h[3]);
  h[2] = __builtin_amdgcn_fmed3f(d, h[1], h[2]);
  h[1] = __builtin_amdgcn_fmed3f(d, h[0], h[1]);
  h[0] = fminf(h[0], d);
}

// merge my sorted-N with partner's (shfl_xor mask) -> sorted-2N
template<int N>
__device__ __forceinline__ void merge_grow(const float (&a)[N], float (&out)[2*N], int mask) {
#pragma unroll
  for (int i = 0; i < N; ++i) out[i] = a[i];
#pragma unroll
  for (int i = 0; i < N; ++i) out[2*N - 1 - i] = __shfl_xor(a[i], mask);
#pragma unroll
  for (int d = N; d >= 1; d >>= 1)
#pragma unroll
    for (int i = 0; i < 2*N; ++i)
      if ((i & d) == 0) ce(out[i], out[i + d]);
}

// keep smallest-16 of two sorted-16 arrays (in-register)
__device__ __forceinline__ void merge16_arr(float (&h)[KSEL], const float (&g)[KSEL]) {
  float c[KSEL];
#pragma unroll
  for (int i = 0; i < KSEL; ++i) c[i] = fminf(h[i], g[KSEL - 1 - i]);
#pragma unroll
  for (int d = 8; d >= 1; d >>= 1)
#pragma unroll
    for (int i = 0; i < KSEL; ++i)
      if ((i & d) == 0) ce(c[i], c[i + d]);
#pragma unroll
  for (int i = 0; i < KSEL; ++i) h[i] = c[i];
}

// ---- DPP row rotation (within 16-lane rows, full-rate VALU) -----------------
template<int K>
__device__ __forceinline__ float rorf(float v) {
  return __int_as_float(
      __builtin_amdgcn_update_dpp(0, __float_as_int(v), 0x120 + K, 0xF, 0xF, false));
}
template<int K>
__device__ __forceinline__ float4 ror4(const float4 v) {
  return make_float4(rorf<K>(v.x), rorf<K>(v.y), rorf<K>(v.z), rorf<K>(v.w));
}

extern "C" __global__ void init_acc(double* acc) {
  const int t = threadIdx.x;
  if (t < 3 * NSLOTS) acc[t] = 0.0;
}

// Block: 512 threads = 8 waves, 16 queries (q = lane&15), rows r = lane>>4.
// Thread's candidates: {it*512 + t}; DPP rotation circulates each row's 16
// candidates so every lane meets 16 pairs per load. 32-way split per query.
extern "C" __global__ __launch_bounds__(THREADS, 8)
void fused_kernel(const float* __restrict__ gts, const float* __restrict__ preds,
                  double* __restrict__ acc) {
  __shared__ float mb[8][QPB][KSEL + 1];
  __shared__ float mbb[8][QPB];

  const int t    = threadIdx.x;
  const int lane = t & 63;
  const int w    = t >> 6;
  const int q    = lane & 15;
  const int b    = blockIdx.y;
  const int pt   = blockIdx.x * QPB + q;

  const float* __restrict__ gq = gts + ((size_t)b * NPTS + pt) * 3;
  const float qx = gq[0], qy = gq[1], qz = gq[2];
  const float qn = fmaf(qx, qx, fmaf(qy, qy, qz * qz));
  const float* __restrict__ pq = preds + ((size_t)b * NPTS + pt) * 3;
  const float px = pq[0], py = pq[1], pz = pq[2];
  const float pn = fmaf(px, px, fmaf(py, py, pz * pz));

  float h1[HSZ], h2[HSZ];
#pragma unroll
  for (int i = 0; i < HSZ; ++i) { h1[i] = 1e30f; h2[i] = 1e30f; }
  float best = 1e30f;

  const float* __restrict__ gb = gts   + (size_t)b * NPTS * 3;
  const float* __restrict__ pb = preds + (size_t)b * NPTS * 3;

#define STEP(CP, CG)                                                          \
  do {                                                                        \
    const float4 _p = (CP), _g = (CG);                                        \
    const float d1 = fmaf(qz, _p.z, fmaf(qy, _p.y, fmaf(qx, _p.x, _p.w)));    \
    insert4(h1, d1);                                                          \
    const float d2 = fmaf(qz, _g.z, fmaf(qy, _g.y, fmaf(qx, _g.x, _g.w)));    \
    insert4(h2, d2);                                                          \
    const float d3 = fmaf(pz, _g.z, fmaf(py, _g.y, fmaf(px, _g.x, _g.w)));    \
    best = fminf(best, d3);                                                   \
  } while (0)

  for (int base = t; base < NPTS; base += THREADS) {   // 8 iterations
    float x = pb[3 * base], y = pb[3 * base + 1], z = pb[3 * base + 2];
    const float4 P = make_float4(-2.f * x, -2.f * y, -2.f * z,
                                 fmaf(x, x, fmaf(y, y, z * z)));
    x = gb[3 * base]; y = gb[3 * base + 1]; z = gb[3 * base + 2];
    const float4 G = make_float4(-2.f * x, -2.f * y, -2.f * z,
                                 fmaf(x, x, fmaf(y, y, z * z)));
    STEP(P, G);
#define R(K) STEP(ror4<K>(P), ror4<K>(G));
    R(1) R(2) R(3) R(4) R(5) R(6) R(7) R(8) R(9) R(10) R(11) R(12) R(13) R(14) R(15)
#undef R
  }
#undef STEP

  // ---- row merge (exact): 4 rows x top-4 -> per-wave sorted-16 -------------
  float f1[KSEL], f2[KSEL];
  { float t8[8]; merge_grow<HSZ>(h1, t8, 16); merge_grow<8>(t8, f1, 32); }
  { float t8[8]; merge_grow<HSZ>(h2, t8, 16); merge_grow<8>(t8, f2, 32); }
  best = fminf(best, __shfl_xor(best, 16));
  best = fminf(best, __shfl_xor(best, 32));

  // ---- cross-wave merge via LDS (buffer reused: h1 round, then h2) ---------
  if (lane < QPB) {
    mbb[w][lane] = best;
#pragma unroll
    for (int i = 0; i < KSEL; ++i) mb[w][lane][i] = f1[i];
  }
  __syncthreads();
  float F1[KSEL], F2[KSEL];
  float bestAll = 1e30f;
  if (w == 0 && lane < QPB) {
#pragma unroll
    for (int i = 0; i < KSEL; ++i) F1[i] = f1[i];
    bestAll = best;
    for (int ww = 1; ww < 8; ++ww) {
      float g[KSEL];
#pragma unroll
      for (int i = 0; i < KSEL; ++i) g[i] = mb[ww][lane][i];
      merge16_arr(F1, g);
      bestAll = fminf(bestAll, mbb[ww][lane]);
    }
  }
  __syncthreads();
  if (lane < QPB) {
#pragma unroll
    for (int i = 0; i < KSEL; ++i) mb[w][lane][i] = f2[i];
  }
  __syncthreads();
  if (w == 0 && lane < QPB) {
#pragma unroll
    for (int i = 0; i < KSEL; ++i) F2[i] = f2[i];
    for (int ww = 1; ww < 8; ++ww) {
      float g[KSEL];
#pragma unroll
      for (int i = 0; i < KSEL; ++i) g[i] = mb[ww][lane][i];
      merge16_arr(F2, g);
    }
    float v1 = bestAll + pn;     // loss_1 term (pred point pt)
    float v2 = F1[0] + qn;       // loss_2 term (gt point pt)
    float v3 = 0.0f;             // density (query norm cancels)
#pragma unroll
    for (int i = 0; i < KSEL; ++i) {
      const float df = F1[i] - F2[i];
      v3 = fmaf(df, df, v3);
    }
#pragma unroll
    for (int off = 8; off >= 1; off >>= 1) {
      v1 += __shfl_xor(v1, off);
      v2 += __shfl_xor(v2, off);
      v3 += __shfl_xor(v3, off);
    }
    if (lane == 0) {
      const int slot = (blockIdx.x + 37 * blockIdx.y) & (NSLOTS - 1);
      atomicAdd(&acc[0 * NSLOTS + slot], (double)v1);
      atomicAdd(&acc[1 * NSLOTS + slot], (double)v2);
      atomicAdd(&acc[2 * NSLOTS + slot], (double)v3);
    }
  }
}

extern "C" __global__ void finalize_kernel(const double* __restrict__ acc,
                                           float* __restrict__ out) {
  const int l = threadIdx.x;  // 64 threads
  double a = acc[l], b = acc[NSLOTS + l], c = acc[2 * NSLOTS + l];
#pragma unroll
  for (int off = 32; off >= 1; off >>= 1) {
    a += __shfl_xor(a, off);
    b += __shfl_xor(b, off);
    c += __shfl_xor(c, off);
  }
  if (l == 0) {
    const double loss1 = a / (double)((size_t)NB * NPTS);
    const double loss2 = b / (double)((size_t)NB * NPTS);
    const double dens  = c / (double)((size_t)NB * NPTS * KSEL);
    out[0] = (float)(loss1 + loss2);
    out[1] = (float)dens;
  }
}

extern "C" void kernel_launch(void* const* d_in, const int* in_sizes, int n_in,
                              void* d_out, int out_size, void* d_ws, size_t ws_size,
                              hipStream_t stream) {
  const float* gts   = (const float*)d_in[0];
  const float* preds = (const float*)d_in[1];
  double* acc = (double*)d_ws;
  float*  out = (float*)d_out;

  hipLaunchKernelGGL(init_acc, dim3(1), dim3(256), 0, stream, acc);
  hipLaunchKernelGGL(fused_kernel, dim3(NPTS / QPB, NB), dim3(THREADS), 0, stream,
                     gts, preds, acc);
  hipLaunchKernelGGL(finalize_kernel, dim3(1), dim3(64), 0, stream, acc, out);
}

// Round 6
// 77.203 us; speedup vs baseline: 2.3741x; 1.8567x over previous
//
#include <hip/hip_runtime.h>
#include <hip/hip_bf16.h>

#define NB      8
#define NPTS    4096
#define KSEL    16
#define HSZ     4            // per-wave-slice list size (16-way split -> top-4 safe)
#define THREADS 1024
#define WV      16           // waves per block = candidate slices
#define CHUNK   (NPTS/WV)    // 256 candidates per wave per array
#define NSLOTS  64
#define HALF    (NB*NPTS)    // 32768 points per array

__device__ __forceinline__ void ce(float& a, float& b) {
  const float lo = fminf(a, b), hi = fmaxf(a, b);
  a = lo; b = hi;
}

// sorted-asc top-4 insert: all reads are old values (descending order), static idx.
__device__ __forceinline__ void insert4(float* h, float d) {
  h[3] = __builtin_amdgcn_fmed3f(d, h[2], h[3]);
  h[2] = __builtin_amdgcn_fmed3f(d, h[1], h[2]);
  h[1] = __builtin_amdgcn_fmed3f(d, h[0], h[1]);
  h[0] = fminf(h[0], d);
}

// In-place grow-merge: h[0..N) sorted asc + g[0..N) sorted asc -> h[0..2N) sorted.
// Concatenate ascending + descending (bitonic), then bitonic-merge network.
template<int N>
__device__ __forceinline__ void grow_ip(float* h, const float* g) {
#pragma unroll
  for (int i = 0; i < N; ++i) h[2 * N - 1 - i] = g[i];
#pragma unroll
  for (int d = N; d >= 1; d >>= 1)
#pragma unroll
    for (int i = 0; i < 2 * N; ++i)
      if ((i & d) == 0) ce(h[i], h[i + d]);
}

// In-place keep-16 merge of two sorted-16 lists.
__device__ __forceinline__ void keep16(float* h, const float* g) {
#pragma unroll
  for (int i = 0; i < KSEL; ++i) h[i] = fminf(h[i], g[KSEL - 1 - i]);
#pragma unroll
  for (int d = 8; d >= 1; d >>= 1)
#pragma unroll
    for (int i = 0; i < KSEL; ++i)
      if ((i & d) == 0) ce(h[i], h[i + d]);
}

// Pack candidates as (-2x, -2y, -2z, |c|^2): distance sans query-norm = 3 fma.
extern "C" __global__ __launch_bounds__(256)
void prep_kernel(const float* __restrict__ gts, const float* __restrict__ preds,
                 float4* __restrict__ pk) {
  const int i = blockIdx.x * 256 + threadIdx.x;   // 0..2*HALF-1
  const float* __restrict__ src = (i < HALF) ? preds : gts;
  const int j = (i < HALF) ? i : i - HALF;
  const float x = src[3 * j], y = src[3 * j + 1], z = src[3 * j + 2];
  pk[i] = make_float4(-2.f * x, -2.f * y, -2.f * z, fmaf(x, x, fmaf(y, y, z * z)));
}

extern "C" __global__ void init_acc(double* acc) {
  const int t = threadIdx.x;
  if (t < 3 * NSLOTS) acc[t] = 0.0;
}

// lane = query point (64/block), wave = candidate-sixteenth (scalar-broadcast stream).
// Hot loop: s_load candidate (scalar pipe) + pure VALU; no LDS, no cross-lane.
extern "C" __global__ __launch_bounds__(THREADS, 8)
void fused_kernel(const float* __restrict__ gts, const float* __restrict__ preds,
                  const float4* __restrict__ pk, double* __restrict__ acc) {
  __shared__ float B1[2048];
  __shared__ float B2[2048];
  __shared__ float BB[512];

  const int t    = threadIdx.x;
  const int lane = t & 63;
  const int w    = __builtin_amdgcn_readfirstlane(t >> 6);  // wave id, uniform
  const int b    = blockIdx.y;
  const int pt   = blockIdx.x * 64 + lane;

  const float* __restrict__ gq = gts + ((size_t)b * NPTS + pt) * 3;
  const float qx = gq[0], qy = gq[1], qz = gq[2];
  const float qn = fmaf(qx, qx, fmaf(qy, qy, qz * qz));
  const float* __restrict__ pq = preds + ((size_t)b * NPTS + pt) * 3;
  const float px = pq[0], py = pq[1], pz = pq[2];
  const float pn = fmaf(px, px, fmaf(py, py, pz * pz));

  float f1[KSEL], f2[KSEL];                 // lists live in [0..4), grow to 16
#pragma unroll
  for (int i = 0; i < HSZ; ++i) { f1[i] = 1e30f; f2[i] = 1e30f; }
  float bw = 1e30f;

  const float4* __restrict__ cp = pk + (size_t)b * NPTS + w * CHUNK;         // preds
  const float4* __restrict__ cg = pk + HALF + (size_t)b * NPTS + w * CHUNK;  // gts

#pragma unroll 4
  for (int j = 0; j < CHUNK; ++j) {
    const float4 c = cp[j];                 // SGPR broadcast (s_load)
    const float d1 = fmaf(qz, c.z, fmaf(qy, c.y, fmaf(qx, c.x, c.w)));
    insert4(f1, d1);
  }
#pragma unroll 4
  for (int j = 0; j < CHUNK; ++j) {
    const float4 c = cg[j];
    const float d2 = fmaf(qz, c.z, fmaf(qy, c.y, fmaf(qx, c.x, c.w)));
    insert4(f2, d2);
    const float d3 = fmaf(pz, c.z, fmaf(py, c.y, fmaf(px, c.x, c.w)));
    bw = fminf(bw, d3);                     // loss_1 partial (query = pred point)
  }

  // ---- 4-level cross-wave merge tree: 16 -> 8 -> 4 -> 2 -> 1 ----------------
  // Level 0: lists of 4
  if (w >= 8) {
    const int s = w - 8;
    float* p1 = &B1[(s * 64 + lane) * HSZ];
    float* p2 = &B2[(s * 64 + lane) * HSZ];
#pragma unroll
    for (int i = 0; i < HSZ; ++i) { p1[i] = f1[i]; p2[i] = f2[i]; }
    BB[s * 64 + lane] = bw;
  }
  __syncthreads();
  if (w < 8) {
    grow_ip<4>(f1, &B1[(w * 64 + lane) * HSZ]);
    grow_ip<4>(f2, &B2[(w * 64 + lane) * HSZ]);
    bw = fminf(bw, BB[w * 64 + lane]);
  }
  __syncthreads();
  // Level 1: lists of 8
  if (w >= 4 && w < 8) {
    const int s = w - 4;
    float* p1 = &B1[(s * 64 + lane) * 8];
    float* p2 = &B2[(s * 64 + lane) * 8];
#pragma unroll
    for (int i = 0; i < 8; ++i) { p1[i] = f1[i]; p2[i] = f2[i]; }
    BB[s * 64 + lane] = bw;
  }
  __syncthreads();
  if (w < 4) {
    grow_ip<8>(f1, &B1[(w * 64 + lane) * 8]);
    grow_ip<8>(f2, &B2[(w * 64 + lane) * 8]);
    bw = fminf(bw, BB[w * 64 + lane]);
  }
  __syncthreads();
  // Level 2: lists of 16
  if (w == 2 || w == 3) {
    const int s = w - 2;
    float* p1 = &B1[(s * 64 + lane) * KSEL];
    float* p2 = &B2[(s * 64 + lane) * KSEL];
#pragma unroll
    for (int i = 0; i < KSEL; ++i) { p1[i] = f1[i]; p2[i] = f2[i]; }
    BB[s * 64 + lane] = bw;
  }
  __syncthreads();
  if (w < 2) {
    keep16(f1, &B1[(w * 64 + lane) * KSEL]);
    keep16(f2, &B2[(w * 64 + lane) * KSEL]);
    bw = fminf(bw, BB[w * 64 + lane]);
  }
  __syncthreads();
  // Level 3: final pair
  if (w == 1) {
    float* p1 = &B1[lane * KSEL];
    float* p2 = &B2[lane * KSEL];
#pragma unroll
    for (int i = 0; i < KSEL; ++i) { p1[i] = f1[i]; p2[i] = f2[i]; }
    BB[lane] = bw;
  }
  __syncthreads();
  if (w == 0) {
    keep16(f1, &B1[lane * KSEL]);
    keep16(f2, &B2[lane * KSEL]);
    bw = fminf(bw, BB[lane]);

    float v1 = bw + pn;       // loss_1 term (pred point pt)
    float v2 = f1[0] + qn;    // loss_2 term (gt point pt)
    float v3 = 0.0f;          // density (query norms cancel)
#pragma unroll
    for (int i = 0; i < KSEL; ++i) {
      const float df = f1[i] - f2[i];
      v3 = fmaf(df, df, v3);
    }
#pragma unroll
    for (int off = 32; off >= 1; off >>= 1) {
      v1 += __shfl_xor(v1, off);
      v2 += __shfl_xor(v2, off);
      v3 += __shfl_xor(v3, off);
    }
    if (lane == 0) {
      const int slot = (blockIdx.x + 13 * blockIdx.y) & (NSLOTS - 1);
      atomicAdd(&acc[0 * NSLOTS + slot], (double)v1);
      atomicAdd(&acc[1 * NSLOTS + slot], (double)v2);
      atomicAdd(&acc[2 * NSLOTS + slot], (double)v3);
    }
  }
}

extern "C" __global__ void finalize_kernel(const double* __restrict__ acc,
                                           float* __restrict__ out) {
  const int l = threadIdx.x;  // 64 threads
  double a = acc[l], b = acc[NSLOTS + l], c = acc[2 * NSLOTS + l];
#pragma unroll
  for (int off = 32; off >= 1; off >>= 1) {
    a += __shfl_xor(a, off);
    b += __shfl_xor(b, off);
    c += __shfl_xor(c, off);
  }
  if (l == 0) {
    const double loss1 = a / (double)((size_t)NB * NPTS);
    const double loss2 = b / (double)((size_t)NB * NPTS);
    const double dens  = c / (double)((size_t)NB * NPTS * KSEL);
    out[0] = (float)(loss1 + loss2);
    out[1] = (float)dens;
  }
}

extern "C" void kernel_launch(void* const* d_in, const int* in_sizes, int n_in,
                              void* d_out, int out_size, void* d_ws, size_t ws_size,
                              hipStream_t stream) {
  const float* gts   = (const float*)d_in[0];
  const float* preds = (const float*)d_in[1];
  float4* pk  = (float4*)d_ws;                          // 2*HALF float4 = 1 MiB
  double* acc = (double*)((char*)d_ws + 2 * HALF * sizeof(float4));
  float*  out = (float*)d_out;

  hipLaunchKernelGGL(prep_kernel, dim3(2 * HALF / 256), dim3(256), 0, stream,
                     gts, preds, pk);
  hipLaunchKernelGGL(init_acc, dim3(1), dim3(256), 0, stream, acc);
  hipLaunchKernelGGL(fused_kernel, dim3(NPTS / 64, NB), dim3(THREADS), 0, stream,
                     gts, preds, pk, acc);
  hipLaunchKernelGGL(finalize_kernel, dim3(1), dim3(64), 0, stream, acc, out);
}